// Round 16
// baseline (782.845 us; speedup 1.0000x reference)
//
#include <hip/hip_runtime.h>
#include <math.h>

// BWNet scan v16: v15 (417us champion: conditional ri0 exchange) with the
// per-step all-reduce rebuilt to minimize MALL RMW serialization:
//  - S-sum and completion counter MERGED into one packed ull per group:
//    bits 52+: count (each block adds 1<<52); bits 0..51: S in fixed point
//    (scale 2^38; per-block Sb<=256 -> 8 adds <= 2^49, no overflow; integer
//    adds commute exactly -> deterministic, replicated flags stay bitwise
//    identical across blocks). Discovery poll IS the payload read.
//  - 4-way split: groups of 8 blocks accumulate into 4 separate 64B lines
//    (pck) + 4 kmax lines. RMW chains 32 -> 8, lines proceed in parallel.
//  - producer: atomicMax(kmx) -> vmcnt(0) -> atomicAdd(pck) (data-before-flag).
//  - consumer: tid0 polls 4 pck lines (count==8 each); 32 lanes broadcast-read
//    4 pck + 4 kmx, combine in-register.
// Everything else v15 verbatim (conditional ri0 epochs, skip-when-done,
// zero-role overlap, cent from read-only keys, 4-rows/thread ar update).

typedef float v4f __attribute__((ext_vector_type(4)));
typedef unsigned long long ull;

#define N_ENT 8192
#define EMB   256
#define KD    32
#define ARD   1024
#define UT    233
#define NSCAN 32
#define NZERO 224
#define NBLK  256

#define FIXSCALE 274877906944.0   // 2^38
#define M52 ((1ull << 52) - 1)

// workspace float-index offsets
#define WS_KEYS 0         // 32*8192 floats, k-major: keys[k*8192+j]
#define WS_C0   262144    // 256: b_a0 + relu(W_fe@um + b_fe)
#define WS_PAIR 262400    // ull region (byte 1049600, 8B aligned)
// ull indices within the pair region
#define PR_RI0W 0         // 2*256: ri0 value words, ping-pong by EPOCH parity
#define PR_CRI0 512       // 65: ri0 completion counters (per epoch)
#define PR_PCK  584       // 64 steps * 4 groups, stride 8 (own 64B line each)
#define PR_KMX  2632      // 64 steps * 4 groups, stride 8
#define NPAIRS  4680

struct Params {
  const float *um, *emask, *enc, *arin, *W_fe, *b_fe, *W_k, *b_k,
              *W_a0, *b_a0, *W_a1, *b_a1, *W_f, *b_f, *W_i0, *b_i0,
              *W_i1, *b_i1, *W_o, *b_o, *ln_g, *ln_b, *W_a3, *b_a3;
  const int* ct;
  float* out;
  float* wsf;
  int*   wsi;
};

__device__ __forceinline__ ull ld_pair(ull* p_) {
  return __hip_atomic_load(p_, __ATOMIC_RELAXED, __HIP_MEMORY_SCOPE_AGENT);
}
__device__ __forceinline__ void st_pair(ull* p_, ull v) {
  __hip_atomic_store(p_, v, __ATOMIC_RELAXED, __HIP_MEMORY_SCOPE_AGENT);
}
__device__ __forceinline__ void wait_ctr(ull* c, ull target) {
  int guard = 0;
  while (__hip_atomic_load(c, __ATOMIC_RELAXED, __HIP_MEMORY_SCOPE_AGENT) < target) {
    __builtin_amdgcn_s_sleep(1);
    if (++guard > (1 << 20)) break;  // failsafe: never hang
  }
}

// ---------------- init: keys GEMM, func_embed, pair-region zero ----------------
__global__ __launch_bounds__(256) void k_init(Params p) {
  __shared__ float enc_s[32 * 260];
  __shared__ float um_s[UT];
  const int tid = threadIdx.x, bid = blockIdx.x;
  float* keys = p.wsf + WS_KEYS;

  if (bid == 0 && tid < UT) um_s[tid] = p.um[tid];
  if (bid == 3) {  // zero ri0 slots, counters, packed accumulators
    ull* pr = (ull*)(p.wsf + WS_PAIR);
    for (int i = tid; i < NPAIRS; i += 256) pr[i] = 0ull;
  }

  const int j0 = bid * 32;
  #pragma unroll
  for (int i = 0; i < 8; ++i) {
    int idx = i * 256 + tid;
    int row = idx >> 6, c4 = idx & 63;
    v4f v = *(const v4f*)(p.enc + (size_t)(j0 + row) * EMB + c4 * 4);
    *(v4f*)&enc_s[row * 260 + c4 * 4] = v;
  }
  __syncthreads();
  {
    const int jl = tid >> 3, kg = tid & 7;
    float acc[4];
    #pragma unroll
    for (int kk = 0; kk < 4; ++kk) acc[kk] = p.b_k[kg * 4 + kk];
    for (int e4 = 0; e4 < 64; ++e4) {
      v4f x = *(const v4f*)&enc_s[jl * 260 + e4 * 4];
      #pragma unroll
      for (int kk = 0; kk < 4; ++kk) {
        v4f w = *(const v4f*)(p.W_k + (size_t)(kg * 4 + kk) * EMB + e4 * 4);
        acc[kk] += x.x * w.x + x.y * w.y + x.z * w.z + x.w * w.w;
      }
    }
    const int j = j0 + jl;
    #pragma unroll
    for (int kk = 0; kk < 4; ++kk) keys[(size_t)(kg * 4 + kk) * N_ENT + j] = acc[kk];
  }
  if (bid == 0) {
    float a = p.b_fe[tid];
    const float* wr = p.W_fe + (size_t)tid * UT;
    for (int u = 0; u < UT; ++u) a += wr[u] * um_s[u];
    p.wsf[WS_C0 + tid] = fmaxf(a, 0.f) + p.b_a0[tid];
  }
}

// ---------------- main: scan (blocks 0..31) + output zeroing (32..255) ----------------
__global__ __launch_bounds__(256, 1) void k_scan(Params p) {
  const int tid = threadIdx.x, bid = blockIdx.x;
  int ctv = p.ct[0];
  const int steps = ctv < 0 ? 0 : (ctv > 64 ? 64 : ctv);
  const size_t NN = (size_t)N_ENT * N_ENT;

  if (bid >= NSCAN) {  // -------- zero role (overlaps the scan; proven) --------
    v4f z = (v4f){0.f, 0.f, 0.f, 0.f};
    v4f* o4 = (v4f*)p.out;
    const size_t tot = NN / 4;
    for (size_t i = (size_t)steps * (N_ENT / 4) + (size_t)(bid - NSCAN) * 256 + tid;
         i < tot; i += (size_t)NZERO * 256)
      __builtin_nontemporal_store(z, o4 + i);
    return;
  }

  // -------- scan role --------
  __shared__ float ar_s[32 * 33];
  __shared__ float ri0_s[8 * 33];
  __shared__ unsigned maskb[256], selb[256];
  __shared__ float x_i1[32], q_s[32], h_s[32], qnf[32];
  __shared__ float garr[128], fog[32], rem[32], og[32], cent[32];
  __shared__ float b_a1s[32], gb_s[128], lng_s[32], lnb_s[32], c0own[8];
  __shared__ float reds[4], rmaxs[4];
  __shared__ int   ridxs[4];
  __shared__ float ssum_s;
  __shared__ int   upd_s, done_s;

  ull* pairb = (ull*)(p.wsf + WS_PAIR);
  ull* ri0w  = pairb + PR_RI0W;
  ull* cri0  = pairb + PR_CRI0;
  ull* pckp  = pairb + PR_PCK;
  ull* kmxp  = pairb + PR_KMX;
  const float* keys = p.wsf + WS_KEYS;

  // ---- preamble: replicated state + weights into LDS / registers ----
  for (int i = tid; i < ARD; i += 256) ar_s[(i >> 5) * 33 + (i & 31)] = p.arin[i];
  {
    unsigned mb = 0u;
    const float* em = p.emask + (size_t)tid * 32;
    #pragma unroll
    for (int j = 0; j < 32; ++j) mb |= (em[j] != 0.f) ? (1u << j) : 0u;
    maskb[tid] = mb; selb[tid] = 0u;
  }
  if (tid < 32) {
    b_a1s[tid] = p.b_a1[tid];
    lng_s[tid] = p.ln_g[tid]; lnb_s[tid] = p.ln_b[tid];
    q_s[tid] = 0.f; h_s[tid] = 0.f; qnf[tid] = 0.f; x_i1[tid] = 0.f;
  }
  if (tid < 128) {
    const int g = tid >> 5, r = tid & 31;
    const float* bg = (g == 0) ? p.b_f : (g == 1) ? p.b_i0 : (g == 2) ? p.b_i1 : p.b_o;
    gb_s[tid] = bg[r];
  }
  if (tid < 8) c0own[tid] = p.wsf[WS_C0 + bid * 8 + tid];
  if (tid == 0) done_s = 0;

  v4f w0[8];  // W_a0 rows [8b,8b+8): thread = (row tid>>5, cols (tid&31)*32..+32)
  { const float* s = p.W_a0 + (size_t)(bid * 8 + (tid >> 5)) * ARD + (tid & 31) * 32;
    #pragma unroll
    for (int i = 0; i < 8; ++i) w0[i] = ((const v4f*)s)[i]; }
  v4f w1[8];  // W_a1: thread = (row tid>>3, cols (tid&7)*32..+32)
  { const float* s = p.W_a1 + (size_t)(tid >> 3) * EMB + (tid & 7) * 32;
    #pragma unroll
    for (int i = 0; i < 8; ++i) w1[i] = ((const v4f*)s)[i]; }
  v4f wg[8];  // LSTM gates: 128 rows x 2 halves
  { const int rowg = tid >> 1, g = rowg >> 5, r = rowg & 31, half = tid & 1;
    const float* W = (g == 0) ? p.W_f : (g == 1) ? p.W_i0 : (g == 2) ? p.W_i1 : p.W_o;
    const float* s = W + r * 64 + half * 32;
    #pragma unroll
    for (int i = 0; i < 8; ++i) wg[i] = ((const v4f*)s)[i]; }
  float kc[32];  // this thread's key column, register-resident
  { const int gcol = bid * 256 + tid;
    #pragma unroll
    for (int k = 0; k < 32; ++k) kc[k] = keys[(size_t)k * N_ENT + gcol]; }
  __syncthreads();

  // produce ri0 slice for epoch e into slot[e&1] (8 rows owned by this block)
  auto produce = [&](int e) {
    const int seg = tid & 31, rl = tid >> 5;
    const float* a = &ar_s[seg * 33];
    float pa = 0.f;
    #pragma unroll
    for (int i = 0; i < 8; ++i) {
      v4f av = *(const v4f*)(a + 4 * i);
      pa += w0[i].x * av.x + w0[i].y * av.y + w0[i].z * av.z + w0[i].w * av.w;
    }
    #pragma unroll
    for (int m = 16; m; m >>= 1) pa += __shfl_xor(pa, m);
    if (seg == 0)
      st_pair(&ri0w[(e & 1) * 256 + bid * 8 + rl],
              (ull)__float_as_uint(fmaxf(pa + c0own[rl], 0.f)));
  };
  produce(0);
  __syncthreads();  // drains vmcnt -> ri0 stores visible before counter bump
  if (tid == 0)
    __hip_atomic_fetch_add(&cri0[0], 1ull, __ATOMIC_RELAXED, __HIP_MEMORY_SCOPE_AGENT);

  int ep = 0;      // last produced epoch (block-uniform)
  int pend = 1;    // 1 if epoch ep not yet consumed (block-uniform)
  float v_reg = 0.f;
  for (int t = 0; t < steps; ++t) {
    const int act = (done_s == 0);

    if (!act) {  // done: zero row, no exchanges, state frozen
      __builtin_nontemporal_store(0.f, p.out + (size_t)t * N_ENT + (bid << 8) + tid);
      continue;
    }

    // ==== Phase A (conditional): consume pending ri0 epoch ====
    if (pend) {
      if (tid == 0) wait_ctr(&cri0[ep], (ull)NSCAN);
      __syncthreads();
      {
        ull u = ld_pair(&ri0w[(ep & 1) * 256 + tid]);
        ri0_s[(tid >> 5) * 33 + (tid & 31)] = __uint_as_float((unsigned)u);
      }
      __syncthreads();
      {  // i1 = relu(W_a1 @ ri0 + b_a1) — only changes when ri0 changed
        const int r = tid >> 3, s8 = tid & 7;
        float p1 = 0.f;
        #pragma unroll
        for (int i = 0; i < 8; ++i) {
          const float* xx = &ri0_s[s8 * 33 + 4 * i];
          p1 += w1[i].x * xx[0] + w1[i].y * xx[1] + w1[i].z * xx[2] + w1[i].w * xx[3];
        }
        #pragma unroll
        for (int m = 4; m; m >>= 1) p1 += __shfl_xor(p1, m);
        if (s8 == 0) x_i1[r] = fmaxf(p1 + b_a1s[r], 0.f);
      }
      __syncthreads();
      pend = 0;
    }

    // ==== LSTM gates / LN / qn (every act step; q evolves) ====
    {  // 4 gate pre-activations
      const int rowg = tid >> 1, g = rowg >> 5, half = tid & 1;
      const float* xsrc = half ? q_s : x_i1;  // x = concat(i1, q)
      float pg = 0.f;
      #pragma unroll
      for (int i = 0; i < 8; ++i)
        pg += wg[i].x * xsrc[4 * i] + wg[i].y * xsrc[4 * i + 1] +
              wg[i].z * xsrc[4 * i + 2] + wg[i].w * xsrc[4 * i + 3];
      pg += __shfl_xor(pg, 1);
      if (!half) {
        pg += gb_s[rowg];
        garr[rowg] = (g == 2) ? tanhf(pg) : 1.f / (1.f + __expf(-pg));
      }
    }
    __syncthreads();
    {  // 3 layernorms in parallel (one per wave)
      const int w = tid >> 6, k = tid & 63;
      if (w < 3 && k < 32) {
        float a = (w == 0) ? garr[k] : (w == 1) ? garr[32 + k] * garr[64 + k] : garr[96 + k];
        float s = a;
        #pragma unroll
        for (int m = 16; m; m >>= 1) s += __shfl_xor(s, m);
        const float mean = s * (1.f / 32.f);
        const float d = a - mean;
        float vv = d * d;
        #pragma unroll
        for (int m = 16; m; m >>= 1) vv += __shfl_xor(vv, m);
        vv *= (1.f / 32.f);
        const float y = d * rsqrtf(vv + 1e-5f) * lng_s[k] + lnb_s[k];
        if (w == 0) fog[k] = y; else if (w == 1) rem[k] = y; else og[k] = y;
      }
    }
    __syncthreads();
    if (tid < 32) {
      const float nh = rem[tid] + fog[tid] * h_s[tid];
      const float qv = tanhf(nh) * og[tid];
      qnf[tid] = qv;
      h_s[tid] = nh; q_s[tid] = qv;  // act==1 here by construction
    }
    __syncthreads();

    // ==== Phase S: sweep over this block's 256 register-resident key cols ====
    {
      float dot = 0.f;
      #pragma unroll
      for (int k = 0; k < 32; ++k) dot += qnf[k] * kc[k];
      const float sig = 1.f / (1.f + __expf(-dot));
      const float v = __expf(__logf(sig) / 0.8f);  // sig^(1/TEMP)
      v_reg = v;
      float sv = v, mv = v;
      int mi = (bid << 8) + tid;
      #pragma unroll
      for (int m = 32; m; m >>= 1) {
        sv += __shfl_xor(sv, m);
        const float ov = __shfl_xor(mv, m);
        const int oi = __shfl_xor(mi, m);
        if (ov > mv || (ov == mv && oi < mi)) { mv = ov; mi = oi; }
      }
      const int wv = tid >> 6;
      if ((tid & 63) == 0) { reds[wv] = sv; rmaxs[wv] = mv; ridxs[wv] = mi; }
    }
    __syncthreads();
    if (tid == 0) {  // split-packed fan-in: max -> drain -> packed add
      float Sb = ((reds[0] + reds[1]) + reds[2]) + reds[3];
      float Mb = rmaxs[0]; int Ib = ridxs[0];
      #pragma unroll
      for (int i2 = 1; i2 < 4; ++i2)
        if (rmaxs[i2] > Mb || (rmaxs[i2] == Mb && ridxs[i2] < Ib)) { Mb = rmaxs[i2]; Ib = ridxs[i2]; }
      const int g = bid >> 3;  // group 0..3
      const ull key = ((ull)__float_as_uint(Mb) << 32) | (ull)(0xFFFFFFFFu - (unsigned)Ib);
      __hip_atomic_fetch_max(&kmxp[(t * 4 + g) * 8], key, __ATOMIC_RELAXED, __HIP_MEMORY_SCOPE_AGENT);
      asm volatile("s_waitcnt vmcnt(0)" ::: "memory");  // kmax before count
      const ull fixedS = (ull)((double)Sb * FIXSCALE);
      __hip_atomic_fetch_add(&pckp[(t * 4 + g) * 8], (1ull << 52) + fixedS,
                             __ATOMIC_RELAXED, __HIP_MEMORY_SCOPE_AGENT);
    }

    // ==== Phase B: tid0 polls 4 packed lines -> lanes combine -> flags ====
    if (tid == 0) {
      int guard = 0;
      for (;;) {
        const ull a = ld_pair(&pckp[(t * 4 + 0) * 8]);
        const ull b = ld_pair(&pckp[(t * 4 + 1) * 8]);
        const ull c = ld_pair(&pckp[(t * 4 + 2) * 8]);
        const ull d = ld_pair(&pckp[(t * 4 + 3) * 8]);
        if (((a >> 52) == 8) & ((b >> 52) == 8) & ((c >> 52) == 8) & ((d >> 52) == 8)) break;
        if (++guard > (1 << 20)) break;
        __builtin_amdgcn_s_sleep(1);
      }
    }
    __syncthreads();
    if (tid < 32) {
      const ull p0 = ld_pair(&pckp[(t * 4 + 0) * 8]);
      const ull p1 = ld_pair(&pckp[(t * 4 + 1) * 8]);
      const ull p2 = ld_pair(&pckp[(t * 4 + 2) * 8]);
      const ull p3 = ld_pair(&pckp[(t * 4 + 3) * 8]);
      const ull k0 = ld_pair(&kmxp[(t * 4 + 0) * 8]);
      const ull k1 = ld_pair(&kmxp[(t * 4 + 1) * 8]);
      const ull k2 = ld_pair(&kmxp[(t * 4 + 2) * 8]);
      const ull k3 = ld_pair(&kmxp[(t * 4 + 3) * 8]);
      const ull fx = (p0 & M52) + (p1 & M52) + (p2 & M52) + (p3 & M52);
      const float s = (float)((double)fx * (1.0 / FIXSCALE));
      ull km = k0;
      if (k1 > km) km = k1;
      if (k2 > km) km = k2;
      if (k3 > km) km = k3;
      const int ii = (int)(0xFFFFFFFFu - (unsigned)(km & 0xFFFFFFFFull));
      const float kv = keys[(size_t)tid * N_ENT + ii];  // keys[:, pick], read-only
      float mn = kv;
      #pragma unroll
      for (int mm = 16; mm; mm >>= 1) mn += __shfl_xor(mn, mm);
      mn *= (1.f / 32.f);
      const float cv = kv - mn;
      cent[tid] = cv;
      const unsigned long long bb = __ballot(cv != cv);
      if (tid == 0) {
        const int valid = (s != 0.f);
        const int nf = (bb == 0) ? 1 : 0;
        const unsigned mw = maskb[ii >> 5];
        const int hit = (valid && ((mw >> (ii & 31)) & 1)) ? 1 : 0;  // act==1 here
        ssum_s = s;
        upd_s = (hit && nf) ? 1 : 0;
        if (hit) {
          maskb[ii >> 5] = mw & ~(1u << (ii & 31));
          selb[ii >> 5] |= (1u << (ii & 31));
          if (!nf) done_s = 1;
        }
      }
    }
    __syncthreads();
    {  // row write for step t (this block's 256 columns)
      const float S = ssum_s;
      const float rowv = (S != 0.f) ? (v_reg / S) : 0.f;
      __builtin_nontemporal_store(rowv, p.out + (size_t)t * N_ENT + (bid << 8) + tid);
    }
    if (upd_s) {  // replicated ar update: 4 rows/thread, W_a3 from L2
      #pragma unroll
      for (int rr = 0; rr < 4; ++rr) {
        const int r = tid + rr * 256;
        const float* wr = p.W_a3 + (size_t)r * KD;
        float dl = p.b_a3[r];
        #pragma unroll
        for (int c4 = 0; c4 < 8; ++c4) {
          v4f wv4 = *(const v4f*)(wr + 4 * c4);
          dl += wv4.x * cent[4 * c4] + wv4.y * cent[4 * c4 + 1] +
                wv4.z * cent[4 * c4 + 2] + wv4.w * cent[4 * c4 + 3];
        }
        if (dl > 0.f) ar_s[(r >> 5) * 33 + (r & 31)] += dl;
      }
    }
    __syncthreads();
    if (upd_s) {  // ar changed -> produce + publish epoch ep+1
      ep += 1;
      produce(ep);
      __syncthreads();  // drains vmcnt -> slice visible before counter bump
      if (tid == 0)
        __hip_atomic_fetch_add(&cri0[ep], 1ull, __ATOMIC_RELAXED, __HIP_MEMORY_SCOPE_AGENT);
      pend = 1;
    }
  }
  __syncthreads();

  // ==== epilogue: sel_out and ar_out (replicated state) ====
  if (bid == 0) {
    for (int i = tid; i < N_ENT; i += 256)
      p.out[NN + i] = ((selb[i >> 5] >> (i & 31)) & 1u) ? 1.f : 0.f;
  } else if (bid == 1) {
    for (int i = tid; i < ARD; i += 256)
      p.out[NN + N_ENT + i] = ar_s[(i >> 5) * 33 + (i & 31)];
  }
}

extern "C" void kernel_launch(void* const* d_in, const int* in_sizes, int n_in,
                              void* d_out, int out_size, void* d_ws, size_t ws_size,
                              hipStream_t stream) {
  (void)in_sizes; (void)n_in; (void)out_size; (void)ws_size;
  Params p;
  p.um    = (const float*)d_in[0];
  p.emask = (const float*)d_in[1];
  p.enc   = (const float*)d_in[2];
  p.arin  = (const float*)d_in[3];
  p.W_fe  = (const float*)d_in[4];
  p.b_fe  = (const float*)d_in[5];
  p.W_k   = (const float*)d_in[6];
  p.b_k   = (const float*)d_in[7];
  p.W_a0  = (const float*)d_in[8];
  p.b_a0  = (const float*)d_in[9];
  p.W_a1  = (const float*)d_in[10];
  p.b_a1  = (const float*)d_in[11];
  p.W_f   = (const float*)d_in[12];
  p.b_f   = (const float*)d_in[13];
  p.W_i0  = (const float*)d_in[14];
  p.b_i0  = (const float*)d_in[15];
  p.W_i1  = (const float*)d_in[16];
  p.b_i1  = (const float*)d_in[17];
  p.W_o   = (const float*)d_in[18];
  p.b_o   = (const float*)d_in[19];
  p.ln_g  = (const float*)d_in[20];
  p.ln_b  = (const float*)d_in[21];
  p.W_a3  = (const float*)d_in[22];
  p.b_a3  = (const float*)d_in[23];
  p.ct    = (const int*)d_in[24];
  p.out   = (float*)d_out;
  p.wsf   = (float*)d_ws;
  p.wsi   = (int*)d_ws;

  hipLaunchKernelGGL(k_init, dim3(NBLK), dim3(256), 0, stream, p);
  hipLaunchKernelGGL(k_scan, dim3(NBLK), dim3(256), 0, stream, p);
}

// Round 17
// 750.114 us; speedup vs baseline: 1.0436x; 1.0436x over previous
//
#include <hip/hip_runtime.h>
#include <math.h>

// BWNet scan v17: v15 (417us champion) with ONE change: the S accumulator and
// the completion counter are merged into one packed ull per step (bits 52+:
// count, each block adds 1<<52; bits 0..51: S in fixed point, scale 2^38;
// 32 blocks * Sb<=256 -> <=2^51, no overflow; integer adds commute exactly ->
// flags stay bitwise-replicated). Producer RMW chains 3 -> 2; tid0's
// discovery poll IS the S payload read. kmax stays a dense array (v15).
// Everything else v15 verbatim: conditional ri0 epochs, skip-when-done,
// zero-role overlap, cent from read-only keys, 4-rows/thread ar update.

typedef float v4f __attribute__((ext_vector_type(4)));
typedef unsigned long long ull;

#define N_ENT 8192
#define EMB   256
#define KD    32
#define ARD   1024
#define UT    233
#define NSCAN 32
#define NZERO 224
#define NBLK  256

#define FIXSCALE 274877906944.0   // 2^38
#define M52 ((1ull << 52) - 1)

// workspace float-index offsets
#define WS_KEYS 0         // 32*8192 floats, k-major: keys[k*8192+j]
#define WS_C0   262144    // 256: b_a0 + relu(W_fe@um + b_fe)
#define WS_PAIR 262400    // ull region (byte 1049600, 8B aligned)
// ull indices within the pair region
#define PR_RI0W 0         // 2*256: ri0 value words, ping-pong by EPOCH parity
#define PR_CRI0 512       // 65: ri0 completion counters (per epoch)
#define PR_KMAX 577       // 64: encoded argmax (v_bits<<32 | (0xFFFFFFFF-idx))
#define PR_PCK  648       // 64 steps, stride 8 (own 64B line each): count|fixedS
#define NPAIRS  1160

struct Params {
  const float *um, *emask, *enc, *arin, *W_fe, *b_fe, *W_k, *b_k,
              *W_a0, *b_a0, *W_a1, *b_a1, *W_f, *b_f, *W_i0, *b_i0,
              *W_i1, *b_i1, *W_o, *b_o, *ln_g, *ln_b, *W_a3, *b_a3;
  const int* ct;
  float* out;
  float* wsf;
  int*   wsi;
};

__device__ __forceinline__ ull ld_pair(ull* p_) {
  return __hip_atomic_load(p_, __ATOMIC_RELAXED, __HIP_MEMORY_SCOPE_AGENT);
}
__device__ __forceinline__ void st_pair(ull* p_, ull v) {
  __hip_atomic_store(p_, v, __ATOMIC_RELAXED, __HIP_MEMORY_SCOPE_AGENT);
}
__device__ __forceinline__ void wait_ctr(ull* c, ull target) {
  int guard = 0;
  while (__hip_atomic_load(c, __ATOMIC_RELAXED, __HIP_MEMORY_SCOPE_AGENT) < target) {
    __builtin_amdgcn_s_sleep(1);
    if (++guard > (1 << 20)) break;  // failsafe: never hang
  }
}

// ---------------- init: keys GEMM, func_embed, pair-region zero ----------------
__global__ __launch_bounds__(256) void k_init(Params p) {
  __shared__ float enc_s[32 * 260];
  __shared__ float um_s[UT];
  const int tid = threadIdx.x, bid = blockIdx.x;
  float* keys = p.wsf + WS_KEYS;

  if (bid == 0 && tid < UT) um_s[tid] = p.um[tid];
  if (bid == 3) {  // zero ri0 slots, counters, kmax, packed accumulators
    ull* pr = (ull*)(p.wsf + WS_PAIR);
    for (int i = tid; i < NPAIRS; i += 256) pr[i] = 0ull;
  }

  const int j0 = bid * 32;
  #pragma unroll
  for (int i = 0; i < 8; ++i) {
    int idx = i * 256 + tid;
    int row = idx >> 6, c4 = idx & 63;
    v4f v = *(const v4f*)(p.enc + (size_t)(j0 + row) * EMB + c4 * 4);
    *(v4f*)&enc_s[row * 260 + c4 * 4] = v;
  }
  __syncthreads();
  {
    const int jl = tid >> 3, kg = tid & 7;
    float acc[4];
    #pragma unroll
    for (int kk = 0; kk < 4; ++kk) acc[kk] = p.b_k[kg * 4 + kk];
    for (int e4 = 0; e4 < 64; ++e4) {
      v4f x = *(const v4f*)&enc_s[jl * 260 + e4 * 4];
      #pragma unroll
      for (int kk = 0; kk < 4; ++kk) {
        v4f w = *(const v4f*)(p.W_k + (size_t)(kg * 4 + kk) * EMB + e4 * 4);
        acc[kk] += x.x * w.x + x.y * w.y + x.z * w.z + x.w * w.w;
      }
    }
    const int j = j0 + jl;
    #pragma unroll
    for (int kk = 0; kk < 4; ++kk) keys[(size_t)(kg * 4 + kk) * N_ENT + j] = acc[kk];
  }
  if (bid == 0) {
    float a = p.b_fe[tid];
    const float* wr = p.W_fe + (size_t)tid * UT;
    for (int u = 0; u < UT; ++u) a += wr[u] * um_s[u];
    p.wsf[WS_C0 + tid] = fmaxf(a, 0.f) + p.b_a0[tid];
  }
}

// ---------------- main: scan (blocks 0..31) + output zeroing (32..255) ----------------
__global__ __launch_bounds__(256, 1) void k_scan(Params p) {
  const int tid = threadIdx.x, bid = blockIdx.x;
  int ctv = p.ct[0];
  const int steps = ctv < 0 ? 0 : (ctv > 64 ? 64 : ctv);
  const size_t NN = (size_t)N_ENT * N_ENT;

  if (bid >= NSCAN) {  // -------- zero role (overlaps the scan; proven) --------
    v4f z = (v4f){0.f, 0.f, 0.f, 0.f};
    v4f* o4 = (v4f*)p.out;
    const size_t tot = NN / 4;
    for (size_t i = (size_t)steps * (N_ENT / 4) + (size_t)(bid - NSCAN) * 256 + tid;
         i < tot; i += (size_t)NZERO * 256)
      __builtin_nontemporal_store(z, o4 + i);
    return;
  }

  // -------- scan role --------
  __shared__ float ar_s[32 * 33];
  __shared__ float ri0_s[8 * 33];
  __shared__ unsigned maskb[256], selb[256];
  __shared__ float x_i1[32], q_s[32], h_s[32], qnf[32];
  __shared__ float garr[128], fog[32], rem[32], og[32], cent[32];
  __shared__ float b_a1s[32], gb_s[128], lng_s[32], lnb_s[32], c0own[8];
  __shared__ float reds[4], rmaxs[4];
  __shared__ int   ridxs[4];
  __shared__ float ssum_s;
  __shared__ int   upd_s, done_s;

  ull* pairb = (ull*)(p.wsf + WS_PAIR);
  ull* ri0w  = pairb + PR_RI0W;
  ull* cri0  = pairb + PR_CRI0;
  ull* kmaxp = pairb + PR_KMAX;
  ull* pckp  = pairb + PR_PCK;
  const float* keys = p.wsf + WS_KEYS;

  // ---- preamble: replicated state + weights into LDS / registers ----
  for (int i = tid; i < ARD; i += 256) ar_s[(i >> 5) * 33 + (i & 31)] = p.arin[i];
  {
    unsigned mb = 0u;
    const float* em = p.emask + (size_t)tid * 32;
    #pragma unroll
    for (int j = 0; j < 32; ++j) mb |= (em[j] != 0.f) ? (1u << j) : 0u;
    maskb[tid] = mb; selb[tid] = 0u;
  }
  if (tid < 32) {
    b_a1s[tid] = p.b_a1[tid];
    lng_s[tid] = p.ln_g[tid]; lnb_s[tid] = p.ln_b[tid];
    q_s[tid] = 0.f; h_s[tid] = 0.f; qnf[tid] = 0.f; x_i1[tid] = 0.f;
  }
  if (tid < 128) {
    const int g = tid >> 5, r = tid & 31;
    const float* bg = (g == 0) ? p.b_f : (g == 1) ? p.b_i0 : (g == 2) ? p.b_i1 : p.b_o;
    gb_s[tid] = bg[r];
  }
  if (tid < 8) c0own[tid] = p.wsf[WS_C0 + bid * 8 + tid];
  if (tid == 0) done_s = 0;

  v4f w0[8];  // W_a0 rows [8b,8b+8): thread = (row tid>>5, cols (tid&31)*32..+32)
  { const float* s = p.W_a0 + (size_t)(bid * 8 + (tid >> 5)) * ARD + (tid & 31) * 32;
    #pragma unroll
    for (int i = 0; i < 8; ++i) w0[i] = ((const v4f*)s)[i]; }
  v4f w1[8];  // W_a1: thread = (row tid>>3, cols (tid&7)*32..+32)
  { const float* s = p.W_a1 + (size_t)(tid >> 3) * EMB + (tid & 7) * 32;
    #pragma unroll
    for (int i = 0; i < 8; ++i) w1[i] = ((const v4f*)s)[i]; }
  v4f wg[8];  // LSTM gates: 128 rows x 2 halves
  { const int rowg = tid >> 1, g = rowg >> 5, r = rowg & 31, half = tid & 1;
    const float* W = (g == 0) ? p.W_f : (g == 1) ? p.W_i0 : (g == 2) ? p.W_i1 : p.W_o;
    const float* s = W + r * 64 + half * 32;
    #pragma unroll
    for (int i = 0; i < 8; ++i) wg[i] = ((const v4f*)s)[i]; }
  float kc[32];  // this thread's key column, register-resident
  { const int gcol = bid * 256 + tid;
    #pragma unroll
    for (int k = 0; k < 32; ++k) kc[k] = keys[(size_t)k * N_ENT + gcol]; }
  __syncthreads();

  // produce ri0 slice for epoch e into slot[e&1] (8 rows owned by this block)
  auto produce = [&](int e) {
    const int seg = tid & 31, rl = tid >> 5;
    const float* a = &ar_s[seg * 33];
    float pa = 0.f;
    #pragma unroll
    for (int i = 0; i < 8; ++i) {
      v4f av = *(const v4f*)(a + 4 * i);
      pa += w0[i].x * av.x + w0[i].y * av.y + w0[i].z * av.z + w0[i].w * av.w;
    }
    #pragma unroll
    for (int m = 16; m; m >>= 1) pa += __shfl_xor(pa, m);
    if (seg == 0)
      st_pair(&ri0w[(e & 1) * 256 + bid * 8 + rl],
              (ull)__float_as_uint(fmaxf(pa + c0own[rl], 0.f)));
  };
  produce(0);
  __syncthreads();  // drains vmcnt -> ri0 stores visible before counter bump
  if (tid == 0)
    __hip_atomic_fetch_add(&cri0[0], 1ull, __ATOMIC_RELAXED, __HIP_MEMORY_SCOPE_AGENT);

  int ep = 0;      // last produced epoch (block-uniform)
  int pend = 1;    // 1 if epoch ep not yet consumed (block-uniform)
  float v_reg = 0.f;
  for (int t = 0; t < steps; ++t) {
    const int act = (done_s == 0);

    if (!act) {  // done: zero row, no exchanges, state frozen
      __builtin_nontemporal_store(0.f, p.out + (size_t)t * N_ENT + (bid << 8) + tid);
      continue;
    }

    // ==== Phase A (conditional): consume pending ri0 epoch ====
    if (pend) {
      if (tid == 0) wait_ctr(&cri0[ep], (ull)NSCAN);
      __syncthreads();
      {
        ull u = ld_pair(&ri0w[(ep & 1) * 256 + tid]);
        ri0_s[(tid >> 5) * 33 + (tid & 31)] = __uint_as_float((unsigned)u);
      }
      __syncthreads();
      {  // i1 = relu(W_a1 @ ri0 + b_a1) — only changes when ri0 changed
        const int r = tid >> 3, s8 = tid & 7;
        float p1 = 0.f;
        #pragma unroll
        for (int i = 0; i < 8; ++i) {
          const float* xx = &ri0_s[s8 * 33 + 4 * i];
          p1 += w1[i].x * xx[0] + w1[i].y * xx[1] + w1[i].z * xx[2] + w1[i].w * xx[3];
        }
        #pragma unroll
        for (int m = 4; m; m >>= 1) p1 += __shfl_xor(p1, m);
        if (s8 == 0) x_i1[r] = fmaxf(p1 + b_a1s[r], 0.f);
      }
      __syncthreads();
      pend = 0;
    }

    // ==== LSTM gates / LN / qn (every act step; q evolves) ====
    {  // 4 gate pre-activations
      const int rowg = tid >> 1, g = rowg >> 5, half = tid & 1;
      const float* xsrc = half ? q_s : x_i1;  // x = concat(i1, q)
      float pg = 0.f;
      #pragma unroll
      for (int i = 0; i < 8; ++i)
        pg += wg[i].x * xsrc[4 * i] + wg[i].y * xsrc[4 * i + 1] +
              wg[i].z * xsrc[4 * i + 2] + wg[i].w * xsrc[4 * i + 3];
      pg += __shfl_xor(pg, 1);
      if (!half) {
        pg += gb_s[rowg];
        garr[rowg] = (g == 2) ? tanhf(pg) : 1.f / (1.f + __expf(-pg));
      }
    }
    __syncthreads();
    {  // 3 layernorms in parallel (one per wave)
      const int w = tid >> 6, k = tid & 63;
      if (w < 3 && k < 32) {
        float a = (w == 0) ? garr[k] : (w == 1) ? garr[32 + k] * garr[64 + k] : garr[96 + k];
        float s = a;
        #pragma unroll
        for (int m = 16; m; m >>= 1) s += __shfl_xor(s, m);
        const float mean = s * (1.f / 32.f);
        const float d = a - mean;
        float vv = d * d;
        #pragma unroll
        for (int m = 16; m; m >>= 1) vv += __shfl_xor(vv, m);
        vv *= (1.f / 32.f);
        const float y = d * rsqrtf(vv + 1e-5f) * lng_s[k] + lnb_s[k];
        if (w == 0) fog[k] = y; else if (w == 1) rem[k] = y; else og[k] = y;
      }
    }
    __syncthreads();
    if (tid < 32) {
      const float nh = rem[tid] + fog[tid] * h_s[tid];
      const float qv = tanhf(nh) * og[tid];
      qnf[tid] = qv;
      h_s[tid] = nh; q_s[tid] = qv;  // act==1 here by construction
    }
    __syncthreads();

    // ==== Phase S: sweep over this block's 256 register-resident key cols ====
    {
      float dot = 0.f;
      #pragma unroll
      for (int k = 0; k < 32; ++k) dot += qnf[k] * kc[k];
      const float sig = 1.f / (1.f + __expf(-dot));
      const float v = __expf(__logf(sig) / 0.8f);  // sig^(1/TEMP)
      v_reg = v;
      float sv = v, mv = v;
      int mi = (bid << 8) + tid;
      #pragma unroll
      for (int m = 32; m; m >>= 1) {
        sv += __shfl_xor(sv, m);
        const float ov = __shfl_xor(mv, m);
        const int oi = __shfl_xor(mi, m);
        if (ov > mv || (ov == mv && oi < mi)) { mv = ov; mi = oi; }
      }
      const int wv = tid >> 6;
      if ((tid & 63) == 0) { reds[wv] = sv; rmaxs[wv] = mv; ridxs[wv] = mi; }
    }
    __syncthreads();
    if (tid == 0) {  // fan-in: kmax RMW -> drain -> packed (count|S) add
      float Sb = ((reds[0] + reds[1]) + reds[2]) + reds[3];
      float Mb = rmaxs[0]; int Ib = ridxs[0];
      #pragma unroll
      for (int i2 = 1; i2 < 4; ++i2)
        if (rmaxs[i2] > Mb || (rmaxs[i2] == Mb && ridxs[i2] < Ib)) { Mb = rmaxs[i2]; Ib = ridxs[i2]; }
      const ull key = ((ull)__float_as_uint(Mb) << 32) | (ull)(0xFFFFFFFFu - (unsigned)Ib);
      __hip_atomic_fetch_max(&kmaxp[t], key, __ATOMIC_RELAXED, __HIP_MEMORY_SCOPE_AGENT);
      asm volatile("s_waitcnt vmcnt(0)" ::: "memory");  // kmax before count
      const ull fixedS = (ull)((double)Sb * FIXSCALE);
      __hip_atomic_fetch_add(&pckp[t * 8], (1ull << 52) + fixedS,
                             __ATOMIC_RELAXED, __HIP_MEMORY_SCOPE_AGENT);
    }

    // ==== Phase B: one-line wait (carries S) -> kmax read -> flags ====
    if (tid == 0) {
      int guard = 0;
      while ((ld_pair(&pckp[t * 8]) >> 52) < (ull)NSCAN) {
        __builtin_amdgcn_s_sleep(1);
        if (++guard > (1 << 20)) break;
      }
    }
    __syncthreads();
    if (tid < 32) {
      const ull pk = ld_pair(&pckp[t * 8]);
      const ull km = ld_pair(&kmaxp[t]);
      const float s = (float)((double)(pk & M52) * (1.0 / FIXSCALE));
      const int ii = (int)(0xFFFFFFFFu - (unsigned)(km & 0xFFFFFFFFull));
      const float kv = keys[(size_t)tid * N_ENT + ii];  // keys[:, pick], read-only
      float mn = kv;
      #pragma unroll
      for (int mm = 16; mm; mm >>= 1) mn += __shfl_xor(mn, mm);
      mn *= (1.f / 32.f);
      const float cv = kv - mn;
      cent[tid] = cv;
      const unsigned long long bb = __ballot(cv != cv);
      if (tid == 0) {
        const int valid = (s != 0.f);
        const int nf = (bb == 0) ? 1 : 0;
        const unsigned mw = maskb[ii >> 5];
        const int hit = (valid && ((mw >> (ii & 31)) & 1)) ? 1 : 0;  // act==1 here
        ssum_s = s;
        upd_s = (hit && nf) ? 1 : 0;
        if (hit) {
          maskb[ii >> 5] = mw & ~(1u << (ii & 31));
          selb[ii >> 5] |= (1u << (ii & 31));
          if (!nf) done_s = 1;
        }
      }
    }
    __syncthreads();
    {  // row write for step t (this block's 256 columns)
      const float S = ssum_s;
      const float rowv = (S != 0.f) ? (v_reg / S) : 0.f;
      __builtin_nontemporal_store(rowv, p.out + (size_t)t * N_ENT + (bid << 8) + tid);
    }
    if (upd_s) {  // replicated ar update: 4 rows/thread, W_a3 from L2
      #pragma unroll
      for (int rr = 0; rr < 4; ++rr) {
        const int r = tid + rr * 256;
        const float* wr = p.W_a3 + (size_t)r * KD;
        float dl = p.b_a3[r];
        #pragma unroll
        for (int c4 = 0; c4 < 8; ++c4) {
          v4f wv4 = *(const v4f*)(wr + 4 * c4);
          dl += wv4.x * cent[4 * c4] + wv4.y * cent[4 * c4 + 1] +
                wv4.z * cent[4 * c4 + 2] + wv4.w * cent[4 * c4 + 3];
        }
        if (dl > 0.f) ar_s[(r >> 5) * 33 + (r & 31)] += dl;
      }
    }
    __syncthreads();
    if (upd_s) {  // ar changed -> produce + publish epoch ep+1
      ep += 1;
      produce(ep);
      __syncthreads();  // drains vmcnt -> slice visible before counter bump
      if (tid == 0)
        __hip_atomic_fetch_add(&cri0[ep], 1ull, __ATOMIC_RELAXED, __HIP_MEMORY_SCOPE_AGENT);
      pend = 1;
    }
  }
  __syncthreads();

  // ==== epilogue: sel_out and ar_out (replicated state) ====
  if (bid == 0) {
    for (int i = tid; i < N_ENT; i += 256)
      p.out[NN + i] = ((selb[i >> 5] >> (i & 31)) & 1u) ? 1.f : 0.f;
  } else if (bid == 1) {
    for (int i = tid; i < ARD; i += 256)
      p.out[NN + N_ENT + i] = ar_s[(i >> 5) * 33 + (i & 31)];
  }
}

extern "C" void kernel_launch(void* const* d_in, const int* in_sizes, int n_in,
                              void* d_out, int out_size, void* d_ws, size_t ws_size,
                              hipStream_t stream) {
  (void)in_sizes; (void)n_in; (void)out_size; (void)ws_size;
  Params p;
  p.um    = (const float*)d_in[0];
  p.emask = (const float*)d_in[1];
  p.enc   = (const float*)d_in[2];
  p.arin  = (const float*)d_in[3];
  p.W_fe  = (const float*)d_in[4];
  p.b_fe  = (const float*)d_in[5];
  p.W_k   = (const float*)d_in[6];
  p.b_k   = (const float*)d_in[7];
  p.W_a0  = (const float*)d_in[8];
  p.b_a0  = (const float*)d_in[9];
  p.W_a1  = (const float*)d_in[10];
  p.b_a1  = (const float*)d_in[11];
  p.W_f   = (const float*)d_in[12];
  p.b_f   = (const float*)d_in[13];
  p.W_i0  = (const float*)d_in[14];
  p.b_i0  = (const float*)d_in[15];
  p.W_i1  = (const float*)d_in[16];
  p.b_i1  = (const float*)d_in[17];
  p.W_o   = (const float*)d_in[18];
  p.b_o   = (const float*)d_in[19];
  p.ln_g  = (const float*)d_in[20];
  p.ln_b  = (const float*)d_in[21];
  p.W_a3  = (const float*)d_in[22];
  p.b_a3  = (const float*)d_in[23];
  p.ct    = (const int*)d_in[24];
  p.out   = (float*)d_out;
  p.wsf   = (float*)d_ws;
  p.wsi   = (int*)d_ws;

  hipLaunchKernelGGL(k_init, dim3(NBLK), dim3(256), 0, stream, p);
  hipLaunchKernelGGL(k_scan, dim3(NBLK), dim3(256), 0, stream, p);
}

// Round 18
// 727.958 us; speedup vs baseline: 1.0754x; 1.0304x over previous
//
#include <hip/hip_runtime.h>
#include <math.h>

// BWNet scan v18: v15 (417us champion) + SPECULATIVE compute pipeline.
// The q/h recurrence is exchange-independent (x_i1 changes only on rare upd
// steps), so after shipping step t's fan-in each block speculatively computes
// qn(t+1)+sweep(t+1)+block-reduce(t+1) DURING the reduce round-trip. Flags are
// bitwise-replicated (same fan-in), so accept/redo is deterministic across
// blocks. On upd: restore q/h backup, consume new ri0 epoch, recompute (old
// hit-path cost). Exchange machinery is v15 verbatim (sacc add + kmax max +
// drain + cpart bump; conditional ri0 epochs; skip-when-done; zero-role).

typedef float v4f __attribute__((ext_vector_type(4)));
typedef unsigned long long ull;

#define N_ENT 8192
#define EMB   256
#define KD    32
#define ARD   1024
#define UT    233
#define NSCAN 32
#define NZERO 224
#define NBLK  256

// workspace float-index offsets
#define WS_KEYS 0         // 32*8192 floats, k-major: keys[k*8192+j]
#define WS_C0   262144    // 256: b_a0 + relu(W_fe@um + b_fe)
#define WS_PAIR 262400    // ull region (byte 1049600, 8B aligned)
// ull indices within the pair region
#define PR_RI0W  0        // 2*256: ri0 value words, ping-pong by EPOCH parity
#define PR_CRI0  512      // 65: ri0 completion counters (per epoch)
#define PR_CPART 577      // 64: partials completion counters (per step)
#define PR_KMAX  641      // 64: encoded argmax (v_bits<<32 | (0xFFFFFFFF-idx))
#define PR_SACC  705      // 32 ulls = 64 floats: S accumulators
#define NPAIRS   737

struct Params {
  const float *um, *emask, *enc, *arin, *W_fe, *b_fe, *W_k, *b_k,
              *W_a0, *b_a0, *W_a1, *b_a1, *W_f, *b_f, *W_i0, *b_i0,
              *W_i1, *b_i1, *W_o, *b_o, *ln_g, *ln_b, *W_a3, *b_a3;
  const int* ct;
  float* out;
  float* wsf;
  int*   wsi;
};

__device__ __forceinline__ ull ld_pair(ull* p_) {
  return __hip_atomic_load(p_, __ATOMIC_RELAXED, __HIP_MEMORY_SCOPE_AGENT);
}
__device__ __forceinline__ void st_pair(ull* p_, ull v) {
  __hip_atomic_store(p_, v, __ATOMIC_RELAXED, __HIP_MEMORY_SCOPE_AGENT);
}
__device__ __forceinline__ void wait_ctr(ull* c, ull target) {
  int guard = 0;
  while (__hip_atomic_load(c, __ATOMIC_RELAXED, __HIP_MEMORY_SCOPE_AGENT) < target) {
    __builtin_amdgcn_s_sleep(1);
    if (++guard > (1 << 20)) break;  // failsafe: never hang
  }
}

// LDS-only barrier: drains lgkmcnt but NOT vmcnt.
__device__ __forceinline__ void bar_lds() {
  asm volatile("s_waitcnt lgkmcnt(0)\n\ts_barrier" ::: "memory");
}

// ---------------- init: keys GEMM, func_embed, pair-region zero ----------------
__global__ __launch_bounds__(256) void k_init(Params p) {
  __shared__ float enc_s[32 * 260];
  __shared__ float um_s[UT];
  const int tid = threadIdx.x, bid = blockIdx.x;
  float* keys = p.wsf + WS_KEYS;

  if (bid == 0 && tid < UT) um_s[tid] = p.um[tid];
  if (bid == 3) {  // zero ri0 slots, counters, kmax, sacc
    ull* pr = (ull*)(p.wsf + WS_PAIR);
    for (int i = tid; i < NPAIRS; i += 256) pr[i] = 0ull;
  }

  const int j0 = bid * 32;
  #pragma unroll
  for (int i = 0; i < 8; ++i) {
    int idx = i * 256 + tid;
    int row = idx >> 6, c4 = idx & 63;
    v4f v = *(const v4f*)(p.enc + (size_t)(j0 + row) * EMB + c4 * 4);
    *(v4f*)&enc_s[row * 260 + c4 * 4] = v;
  }
  __syncthreads();
  {
    const int jl = tid >> 3, kg = tid & 7;
    float acc[4];
    #pragma unroll
    for (int kk = 0; kk < 4; ++kk) acc[kk] = p.b_k[kg * 4 + kk];
    for (int e4 = 0; e4 < 64; ++e4) {
      v4f x = *(const v4f*)&enc_s[jl * 260 + e4 * 4];
      #pragma unroll
      for (int kk = 0; kk < 4; ++kk) {
        v4f w = *(const v4f*)(p.W_k + (size_t)(kg * 4 + kk) * EMB + e4 * 4);
        acc[kk] += x.x * w.x + x.y * w.y + x.z * w.z + x.w * w.w;
      }
    }
    const int j = j0 + jl;
    #pragma unroll
    for (int kk = 0; kk < 4; ++kk) keys[(size_t)(kg * 4 + kk) * N_ENT + j] = acc[kk];
  }
  if (bid == 0) {
    float a = p.b_fe[tid];
    const float* wr = p.W_fe + (size_t)tid * UT;
    for (int u = 0; u < UT; ++u) a += wr[u] * um_s[u];
    p.wsf[WS_C0 + tid] = fmaxf(a, 0.f) + p.b_a0[tid];
  }
}

// ---------------- main: scan (blocks 0..31) + output zeroing (32..255) ----------------
__global__ __launch_bounds__(256, 1) void k_scan(Params p) {
  const int tid = threadIdx.x, bid = blockIdx.x;
  int ctv = p.ct[0];
  const int steps = ctv < 0 ? 0 : (ctv > 64 ? 64 : ctv);
  const size_t NN = (size_t)N_ENT * N_ENT;

  if (bid >= NSCAN) {  // -------- zero role (overlaps the scan; proven) --------
    v4f z = (v4f){0.f, 0.f, 0.f, 0.f};
    v4f* o4 = (v4f*)p.out;
    const size_t tot = NN / 4;
    for (size_t i = (size_t)steps * (N_ENT / 4) + (size_t)(bid - NSCAN) * 256 + tid;
         i < tot; i += (size_t)NZERO * 256)
      __builtin_nontemporal_store(z, o4 + i);
    return;
  }

  // -------- scan role --------
  __shared__ float ar_s[32 * 33];
  __shared__ float ri0_s[8 * 33];
  __shared__ unsigned maskb[256], selb[256];
  __shared__ float x_i1[32], q_s[32], h_s[32], qnf[32];
  __shared__ float q_bak[32], h_bak[32];
  __shared__ float garr[128], fog[32], rem[32], og[32], cent[32];
  __shared__ float b_a1s[32], gb_s[128], lng_s[32], lnb_s[32], c0own[8];
  __shared__ float reds[4], rmaxs[4];
  __shared__ int   ridxs[4];
  __shared__ float ssum_s;
  __shared__ int   upd_s, done_s;

  ull*   pairb = (ull*)(p.wsf + WS_PAIR);
  ull*   ri0w  = pairb + PR_RI0W;
  ull*   cri0  = pairb + PR_CRI0;
  ull*   cpart = pairb + PR_CPART;
  ull*   kmaxp = pairb + PR_KMAX;
  float* saccp = (float*)(pairb + PR_SACC);
  const float* keys = p.wsf + WS_KEYS;

  // ---- preamble: replicated state + weights into LDS / registers ----
  for (int i = tid; i < ARD; i += 256) ar_s[(i >> 5) * 33 + (i & 31)] = p.arin[i];
  {
    unsigned mb = 0u;
    const float* em = p.emask + (size_t)tid * 32;
    #pragma unroll
    for (int j = 0; j < 32; ++j) mb |= (em[j] != 0.f) ? (1u << j) : 0u;
    maskb[tid] = mb; selb[tid] = 0u;
  }
  if (tid < 32) {
    b_a1s[tid] = p.b_a1[tid];
    lng_s[tid] = p.ln_g[tid]; lnb_s[tid] = p.ln_b[tid];
    q_s[tid] = 0.f; h_s[tid] = 0.f; qnf[tid] = 0.f; x_i1[tid] = 0.f;
  }
  if (tid < 128) {
    const int g = tid >> 5, r = tid & 31;
    const float* bg = (g == 0) ? p.b_f : (g == 1) ? p.b_i0 : (g == 2) ? p.b_i1 : p.b_o;
    gb_s[tid] = bg[r];
  }
  if (tid < 8) c0own[tid] = p.wsf[WS_C0 + bid * 8 + tid];
  if (tid == 0) done_s = 0;

  v4f w0[8];  // W_a0 rows [8b,8b+8)
  { const float* s = p.W_a0 + (size_t)(bid * 8 + (tid >> 5)) * ARD + (tid & 31) * 32;
    #pragma unroll
    for (int i = 0; i < 8; ++i) w0[i] = ((const v4f*)s)[i]; }
  v4f w1[8];  // W_a1
  { const float* s = p.W_a1 + (size_t)(tid >> 3) * EMB + (tid & 7) * 32;
    #pragma unroll
    for (int i = 0; i < 8; ++i) w1[i] = ((const v4f*)s)[i]; }
  v4f wg[8];  // LSTM gates
  { const int rowg = tid >> 1, g = rowg >> 5, r = rowg & 31, half = tid & 1;
    const float* W = (g == 0) ? p.W_f : (g == 1) ? p.W_i0 : (g == 2) ? p.W_i1 : p.W_o;
    const float* s = W + r * 64 + half * 32;
    #pragma unroll
    for (int i = 0; i < 8; ++i) wg[i] = ((const v4f*)s)[i]; }
  float kc[32];  // this thread's key column, register-resident
  { const int gcol = bid * 256 + tid;
    #pragma unroll
    for (int k = 0; k < 32; ++k) kc[k] = keys[(size_t)k * N_ENT + gcol]; }
  __syncthreads();

  auto produce = [&](int e) {
    const int seg = tid & 31, rl = tid >> 5;
    const float* a = &ar_s[seg * 33];
    float pa = 0.f;
    #pragma unroll
    for (int i = 0; i < 8; ++i) {
      v4f av = *(const v4f*)(a + 4 * i);
      pa += w0[i].x * av.x + w0[i].y * av.y + w0[i].z * av.z + w0[i].w * av.w;
    }
    #pragma unroll
    for (int m = 16; m; m >>= 1) pa += __shfl_xor(pa, m);
    if (seg == 0)
      st_pair(&ri0w[(e & 1) * 256 + bid * 8 + rl],
              (ull)__float_as_uint(fmaxf(pa + c0own[rl], 0.f)));
  };
  auto consume_ri0 = [&](int e) {
    if (tid == 0) wait_ctr(&cri0[e], (ull)NSCAN);
    bar_lds();
    {
      ull u = ld_pair(&ri0w[(e & 1) * 256 + tid]);
      ri0_s[(tid >> 5) * 33 + (tid & 31)] = __uint_as_float((unsigned)u);
    }
    bar_lds();
    {  // i1 = relu(W_a1 @ ri0 + b_a1)
      const int r = tid >> 3, s8 = tid & 7;
      float p1 = 0.f;
      #pragma unroll
      for (int i = 0; i < 8; ++i) {
        const float* xx = &ri0_s[s8 * 33 + 4 * i];
        p1 += w1[i].x * xx[0] + w1[i].y * xx[1] + w1[i].z * xx[2] + w1[i].w * xx[3];
      }
      #pragma unroll
      for (int m = 4; m; m >>= 1) p1 += __shfl_xor(p1, m);
      if (s8 == 0) x_i1[r] = fmaxf(p1 + b_a1s[r], 0.f);
    }
    bar_lds();
  };
  auto compute_qn = [&]() {  // gates -> 3 LNs -> qn; advances q_s/h_s
    {
      const int rowg = tid >> 1, g = rowg >> 5, half = tid & 1;
      const float* xsrc = half ? q_s : x_i1;
      float pg = 0.f;
      #pragma unroll
      for (int i = 0; i < 8; ++i)
        pg += wg[i].x * xsrc[4 * i] + wg[i].y * xsrc[4 * i + 1] +
              wg[i].z * xsrc[4 * i + 2] + wg[i].w * xsrc[4 * i + 3];
      pg += __shfl_xor(pg, 1);
      if (!half) {
        pg += gb_s[rowg];
        garr[rowg] = (g == 2) ? tanhf(pg) : 1.f / (1.f + __expf(-pg));
      }
    }
    bar_lds();
    {
      const int w = tid >> 6, k = tid & 63;
      if (w < 3 && k < 32) {
        float a = (w == 0) ? garr[k] : (w == 1) ? garr[32 + k] * garr[64 + k] : garr[96 + k];
        float s = a;
        #pragma unroll
        for (int m = 16; m; m >>= 1) s += __shfl_xor(s, m);
        const float mean = s * (1.f / 32.f);
        const float d = a - mean;
        float vv = d * d;
        #pragma unroll
        for (int m = 16; m; m >>= 1) vv += __shfl_xor(vv, m);
        vv *= (1.f / 32.f);
        const float y = d * rsqrtf(vv + 1e-5f) * lng_s[k] + lnb_s[k];
        if (w == 0) fog[k] = y; else if (w == 1) rem[k] = y; else og[k] = y;
      }
    }
    bar_lds();
    if (tid < 32) {
      const float nh = rem[tid] + fog[tid] * h_s[tid];
      const float qv = tanhf(nh) * og[tid];
      qnf[tid] = qv;
      h_s[tid] = nh; q_s[tid] = qv;
    }
    bar_lds();
  };
  auto sweep_reduce = [&]() -> float {  // fills reds/rmaxs/ridxs; returns v
    float dot = 0.f;
    #pragma unroll
    for (int k = 0; k < 32; ++k) dot += qnf[k] * kc[k];
    const float sig = 1.f / (1.f + __expf(-dot));
    const float v = __expf(__logf(sig) / 0.8f);  // sig^(1/TEMP)
    float sv = v, mv = v;
    int mi = (bid << 8) + tid;
    #pragma unroll
    for (int m = 32; m; m >>= 1) {
      sv += __shfl_xor(sv, m);
      const float ov = __shfl_xor(mv, m);
      const int oi = __shfl_xor(mi, m);
      if (ov > mv || (ov == mv && oi < mi)) { mv = ov; mi = oi; }
    }
    const int wv = tid >> 6;
    if ((tid & 63) == 0) { reds[wv] = sv; rmaxs[wv] = mv; ridxs[wv] = mi; }
    bar_lds();
    return v;
  };

  // ---- prologue: epoch 0 -> x_i1; qn(0); sweep(0) ----
  produce(0);
  __syncthreads();  // drains vmcnt -> ri0 stores visible before bump
  if (tid == 0)
    __hip_atomic_fetch_add(&cri0[0], 1ull, __ATOMIC_RELAXED, __HIP_MEMORY_SCOPE_AGENT);
  consume_ri0(0);
  compute_qn();
  float v_cur = sweep_reduce();
  int ep = 0;

  for (int t = 0; t < steps; ++t) {
    if (done_s != 0) {  // done: zero row, no exchanges
      __builtin_nontemporal_store(0.f, p.out + (size_t)t * N_ENT + (bid << 8) + tid);
      continue;
    }

    // ==== ship fan-in for step t (from current reds/rmaxs/ridxs) ====
    if (tid == 0) {
      float Sb = ((reds[0] + reds[1]) + reds[2]) + reds[3];
      float Mb = rmaxs[0]; int Ib = ridxs[0];
      #pragma unroll
      for (int i2 = 1; i2 < 4; ++i2)
        if (rmaxs[i2] > Mb || (rmaxs[i2] == Mb && ridxs[i2] < Ib)) { Mb = rmaxs[i2]; Ib = ridxs[i2]; }
      __hip_atomic_fetch_add(&saccp[t], Sb, __ATOMIC_RELAXED, __HIP_MEMORY_SCOPE_AGENT);
      const ull key = ((ull)__float_as_uint(Mb) << 32) | (ull)(0xFFFFFFFFu - (unsigned)Ib);
      __hip_atomic_fetch_max(&kmaxp[t], key, __ATOMIC_RELAXED, __HIP_MEMORY_SCOPE_AGENT);
      asm volatile("s_waitcnt vmcnt(0)" ::: "memory");  // data before flag
      __hip_atomic_fetch_add(&cpart[t], 1ull, __ATOMIC_RELAXED, __HIP_MEMORY_SCOPE_AGENT);
    }

    // ==== speculative compute for t+1 (assumes x_i1 unchanged) ====
    if (tid < 32) { q_bak[tid] = q_s[tid]; h_bak[tid] = h_s[tid]; }
    bar_lds();
    compute_qn();
    float v_spec = sweep_reduce();

    // ==== wait + flags for step t ====
    if (tid == 0) wait_ctr(&cpart[t], (ull)NSCAN);
    bar_lds();
    if (tid < 32) {
      const float s = __hip_atomic_load(&saccp[t], __ATOMIC_RELAXED, __HIP_MEMORY_SCOPE_AGENT);
      const ull km = ld_pair(&kmaxp[t]);
      const int ii = (int)(0xFFFFFFFFu - (unsigned)(km & 0xFFFFFFFFull));
      const float kv = keys[(size_t)tid * N_ENT + ii];  // keys[:, pick]
      float mn = kv;
      #pragma unroll
      for (int mm = 16; mm; mm >>= 1) mn += __shfl_xor(mn, mm);
      mn *= (1.f / 32.f);
      const float cv = kv - mn;
      cent[tid] = cv;
      const unsigned long long bb = __ballot(cv != cv);
      if (tid == 0) {
        const int valid = (s != 0.f);
        const int nf = (bb == 0) ? 1 : 0;
        const unsigned mw = maskb[ii >> 5];
        const int hit = (valid && ((mw >> (ii & 31)) & 1)) ? 1 : 0;
        ssum_s = s;
        upd_s = (hit && nf) ? 1 : 0;
        if (hit) {
          maskb[ii >> 5] = mw & ~(1u << (ii & 31));
          selb[ii >> 5] |= (1u << (ii & 31));
          if (!nf) done_s = 1;
        }
      }
    }
    bar_lds();
    {  // row write for step t (never drained in-loop)
      const float S = ssum_s;
      const float rowv = (S != 0.f) ? (v_cur / S) : 0.f;
      __builtin_nontemporal_store(rowv, p.out + (size_t)t * N_ENT + (bid << 8) + tid);
    }
    if (upd_s) {  // rare: ar changed -> new epoch -> restore q/h -> recompute
      #pragma unroll
      for (int rr = 0; rr < 4; ++rr) {
        const int r = tid + rr * 256;
        const float* wr = p.W_a3 + (size_t)r * KD;
        float dl = p.b_a3[r];
        #pragma unroll
        for (int c4 = 0; c4 < 8; ++c4) {
          v4f wv4 = *(const v4f*)(wr + 4 * c4);
          dl += wv4.x * cent[4 * c4] + wv4.y * cent[4 * c4 + 1] +
                wv4.z * cent[4 * c4 + 2] + wv4.w * cent[4 * c4 + 3];
        }
        if (dl > 0.f) ar_s[(r >> 5) * 33 + (r & 31)] += dl;
      }
      bar_lds();
      ep += 1;
      produce(ep);
      __syncthreads();  // drains vmcnt -> slice visible before bump
      if (tid == 0)
        __hip_atomic_fetch_add(&cri0[ep], 1ull, __ATOMIC_RELAXED, __HIP_MEMORY_SCOPE_AGENT);
      consume_ri0(ep);
      if (tid < 32) { q_s[tid] = q_bak[tid]; h_s[tid] = h_bak[tid]; }
      bar_lds();
      compute_qn();
      v_spec = sweep_reduce();
    }
    v_cur = v_spec;  // accept (speculative or recomputed) t+1 state
  }
  __syncthreads();

  // ==== epilogue: sel_out and ar_out (replicated state) ====
  if (bid == 0) {
    for (int i = tid; i < N_ENT; i += 256)
      p.out[NN + i] = ((selb[i >> 5] >> (i & 31)) & 1u) ? 1.f : 0.f;
  } else if (bid == 1) {
    for (int i = tid; i < ARD; i += 256)
      p.out[NN + N_ENT + i] = ar_s[(i >> 5) * 33 + (i & 31)];
  }
}

extern "C" void kernel_launch(void* const* d_in, const int* in_sizes, int n_in,
                              void* d_out, int out_size, void* d_ws, size_t ws_size,
                              hipStream_t stream) {
  (void)in_sizes; (void)n_in; (void)out_size; (void)ws_size;
  Params p;
  p.um    = (const float*)d_in[0];
  p.emask = (const float*)d_in[1];
  p.enc   = (const float*)d_in[2];
  p.arin  = (const float*)d_in[3];
  p.W_fe  = (const float*)d_in[4];
  p.b_fe  = (const float*)d_in[5];
  p.W_k   = (const float*)d_in[6];
  p.b_k   = (const float*)d_in[7];
  p.W_a0  = (const float*)d_in[8];
  p.b_a0  = (const float*)d_in[9];
  p.W_a1  = (const float*)d_in[10];
  p.b_a1  = (const float*)d_in[11];
  p.W_f   = (const float*)d_in[12];
  p.b_f   = (const float*)d_in[13];
  p.W_i0  = (const float*)d_in[14];
  p.b_i0  = (const float*)d_in[15];
  p.W_i1  = (const float*)d_in[16];
  p.b_i1  = (const float*)d_in[17];
  p.W_o   = (const float*)d_in[18];
  p.b_o   = (const float*)d_in[19];
  p.ln_g  = (const float*)d_in[20];
  p.ln_b  = (const float*)d_in[21];
  p.W_a3  = (const float*)d_in[22];
  p.b_a3  = (const float*)d_in[23];
  p.ct    = (const int*)d_in[24];
  p.out   = (float*)d_out;
  p.wsf   = (float*)d_ws;
  p.wsi   = (int*)d_ws;

  hipLaunchKernelGGL(k_init, dim3(NBLK), dim3(256), 0, stream, p);
  hipLaunchKernelGGL(k_scan, dim3(NBLK), dim3(256), 0, stream, p);
}